// Round 2
// baseline (721.484 us; speedup 1.0000x reference)
//
#include <hip/hip_runtime.h>

// B=64, C=2, N=1024, T=13, D=256
// out: [B,N,N] fp32 = 268 MB; ws: centered ranks as bf16 bits [B,N,D] u16 = 32 MB

typedef __attribute__((ext_vector_type(4))) float f32x4;
typedef __attribute__((ext_vector_type(8))) short bf16x8;

__device__ __forceinline__ void load_lds16(const void* g, void* l) {
  __builtin_amdgcn_global_load_lds(
      (const __attribute__((address_space(1))) void*)g,
      (__attribute__((address_space(3))) void*)l, 16, 0, 0);
}

// ---------------------------------------------------------------------------
// K1: conv (bcnt,dct->bnd) + time-LayerNorm + Spearman rank -> (rank-128) bf16
// ONE WAVE PER ROW, 4 dims per lane. Rank counting via v_readlane broadcast
// (SGPR operand of v_cmp) -> pure-VALU, no LDS-pipe bottleneck.
// ---------------------------------------------------------------------------
__global__ __launch_bounds__(256) void conv_rank_kernel(
    const float* __restrict__ x, const float* __restrict__ w,
    const float* __restrict__ cb, const float* __restrict__ tg,
    const float* __restrict__ tb, unsigned short* __restrict__ ranks)
{
  int tid = threadIdx.x;
  int wv = tid >> 6, lane = tid & 63;
  int row = blockIdx.x * 4 + wv;     // grid = 16384 blocks, 4 rows/block
  int d0 = lane * 4;

  // stage x[b,:,n,:] (26 floats) for each of the block's 4 rows
  __shared__ float xs[4][26];
  if (tid < 104) {
    int r = tid / 26, i = tid - r * 26;
    int rr = blockIdx.x * 4 + r;
    int bb = rr >> 10, nn = rr & 1023;
    int c = i / 13, t = i - c * 13;
    xs[r][i] = x[((size_t)(bb * 2 + c) * 1024 + nn) * 13 + t];
  }
  __syncthreads();

  // conv: e[s] = cb[d0+s] + sum_i w[d0+s, i] * xs[wv][i]   (i = c*13+t, 26)
  float4 cbv = ((const float4*)cb)[lane];
  float e[4];
  #pragma unroll
  for (int s = 0; s < 4; ++s) {
    const float* wd = w + (size_t)(d0 + s) * 26;
    float a = (&cbv.x)[s];
    #pragma unroll
    for (int i = 0; i < 26; ++i) a += wd[i] * xs[wv][i];
    e[s] = a;
  }

  // time layernorm over D=256 (wave butterfly reduction)
  float s1 = e[0] + e[1] + e[2] + e[3];
  float s2 = e[0]*e[0] + e[1]*e[1] + e[2]*e[2] + e[3]*e[3];
  #pragma unroll
  for (int o = 32; o > 0; o >>= 1) {
    s1 += __shfl_xor(s1, o);
    s2 += __shfl_xor(s2, o);
  }
  float mu = s1 * (1.0f / 256.0f);
  float var = s2 * (1.0f / 256.0f) - mu * mu;
  float rs = rsqrtf(var + 1e-5f);

  float4 tgv = ((const float4*)tg)[lane];
  float4 tbv = ((const float4*)tb)[lane];
  unsigned int k[4];
  #pragma unroll
  for (int s = 0; s < 4; ++s) {
    float val = (e[s] - mu) * rs * (&tgv.x)[s] + (&tbv.x)[s];
    unsigned int u = __float_as_uint(val);
    // monotone sortable key: u ^ (asr(u,31) | 0x80000000)
    k[s] = u ^ ((unsigned int)((int)u >> 31) | 0x80000000u);
  }

  // rank counting: all 256 keys live in this wave's VGPRs.
  // broadcast lane j's 4 keys via v_readlane (uniform -> SGPR), cmp+addc.
  int c0 = 0, c1 = 0, c2 = 0, c3 = 0;
  #pragma unroll 4
  for (int j = 0; j < 64; ++j) {
    unsigned int q0 = (unsigned int)__builtin_amdgcn_readlane((int)k[0], j);
    unsigned int q1 = (unsigned int)__builtin_amdgcn_readlane((int)k[1], j);
    unsigned int q2 = (unsigned int)__builtin_amdgcn_readlane((int)k[2], j);
    unsigned int q3 = (unsigned int)__builtin_amdgcn_readlane((int)k[3], j);
    c0 += (int)(q0 < k[0]) + (int)(q1 < k[0]) + (int)(q2 < k[0]) + (int)(q3 < k[0]);
    c1 += (int)(q0 < k[1]) + (int)(q1 < k[1]) + (int)(q2 < k[1]) + (int)(q3 < k[1]);
    c2 += (int)(q0 < k[2]) + (int)(q1 < k[2]) + (int)(q2 < k[2]) + (int)(q3 < k[2]);
    c3 += (int)(q0 < k[3]) + (int)(q1 < k[3]) + (int)(q2 < k[3]) + (int)(q3 < k[3]);
  }

  // r' = rank - 128 in [-128,127]: exact in bf16 (low 16 fp32 bits are 0)
  ushort4 out;
  out.x = (unsigned short)(__float_as_uint((float)(c0 - 128)) >> 16);
  out.y = (unsigned short)(__float_as_uint((float)(c1 - 128)) >> 16);
  out.z = (unsigned short)(__float_as_uint((float)(c2 - 128)) >> 16);
  out.w = (unsigned short)(__float_as_uint((float)(c3 - 128)) >> 16);
  *(ushort4*)(ranks + (size_t)row * 256 + d0) = out;
}

// ---------------------------------------------------------------------------
// K2: per batch S = R R^T (bf16 MFMA), adj = |S-64| / (norm^2+1e-8)
// SYMMETRIC: only upper-triangle tiles (ti<=tj), off-diag tiles write both
// the tile and its transpose (transpose store is per-lane float4-contiguous).
// m97 structure: 128x128 tile, BK=64, global_load_lds width 16.
// ---------------------------------------------------------------------------
__global__ __launch_bounds__(256) void corr_kernel(
    const unsigned short* __restrict__ ranks, float* __restrict__ out)
{
  int blk = blockIdx.x;
  int b = blk / 36;
  int t = blk - b * 36;
  int ti = 0, rem = t;
  while (rem >= 8 - ti) { rem -= 8 - ti; ++ti; }   // uniform tiny loop
  int tj = ti + rem;
  int trow = ti << 7;
  int tcol = tj << 7;
  const unsigned short* R = ranks + (size_t)b * 1024 * 256;
  float* O = out + (size_t)b * 1024 * 1024;

  __shared__ __align__(16) unsigned short As[128 * 64];
  __shared__ __align__(16) unsigned short Bs[128 * 64];

  int tid = threadIdx.x;
  int wave = tid >> 6, lane = tid & 63;
  int wrow = (wave >> 1) * 64, wcol = (wave & 1) * 64;

  f32x4 acc[4][4] = {};

  for (int kt = 0; kt < 4; ++kt) {
    int k0 = kt * 64;
    #pragma unroll
    for (int q = 0; q < 4; ++q) {
      int elem = q * 2048 + tid * 8;   // wave-contiguous: base + lane*8 elems
      int r = elem >> 6;
      int c = elem & 63;
      load_lds16(R + (size_t)(trow + r) * 256 + k0 + c, As + elem);
      load_lds16(R + (size_t)(tcol + r) * 256 + k0 + c, Bs + elem);
    }
    __syncthreads();

    #pragma unroll
    for (int ks2 = 0; ks2 < 2; ++ks2) {
      int kk = ks2 * 32 + ((lane >> 4) << 3);   // A/B frag: k = quad*8 + j
      bf16x8 af[4], bf[4];
      #pragma unroll
      for (int mi = 0; mi < 4; ++mi)
        af[mi] = *(const bf16x8*)(As + (wrow + mi * 16 + (lane & 15)) * 64 + kk);
      #pragma unroll
      for (int ni = 0; ni < 4; ++ni)
        bf[ni] = *(const bf16x8*)(Bs + (wcol + ni * 16 + (lane & 15)) * 64 + kk);
      #pragma unroll
      for (int mi = 0; mi < 4; ++mi) {
        #pragma unroll
        for (int ni = 0; ni < 4; ++ni)
          acc[mi][ni] = __builtin_amdgcn_mfma_f32_16x16x32_bf16(
              af[mi], bf[ni], acc[mi][ni], 0, 0, 0);
      }
    }
    __syncthreads();
  }

  // corr = S - 64 (exact); denom = norm^2 + 1e-8, norm^2 = 1398080
  float inv_den = 1.0f / (1398080.0f + 1e-8f);
  bool offdiag = (ti != tj);
  #pragma unroll
  for (int mi = 0; mi < 4; ++mi) {
    int r0 = trow + wrow + mi * 16 + ((lane >> 4) << 2);  // C/D: row=quad*4+reg
    #pragma unroll
    for (int ni = 0; ni < 4; ++ni) {
      int c0 = tcol + wcol + ni * 16 + (lane & 15);       // C/D: col=lane&15
      float4 tv;
      #pragma unroll
      for (int v = 0; v < 4; ++v) {
        float adj = fabsf(acc[mi][ni][v] - 64.0f) * inv_den;
        O[(size_t)(r0 + v) * 1024 + c0] = adj;
        (&tv.x)[v] = adj;
      }
      if (offdiag)   // transpose: row c0, cols r0..r0+3 (16B-aligned float4)
        *(float4*)(O + (size_t)c0 * 1024 + r0) = tv;
    }
  }
}

// ---------------------------------------------------------------------------
// K3: in-place LayerNorm over last axis (N=1024) + static_g/static_b + ReLU
// one block per row, thread = one float4
// ---------------------------------------------------------------------------
__global__ __launch_bounds__(256) void ln_relu_kernel(
    float* __restrict__ out, const float* __restrict__ sg,
    const float* __restrict__ sb)
{
  size_t row = blockIdx.x;
  float* p = out + row * 1024;
  int tid = threadIdx.x;
  int wave = tid >> 6, lane = tid & 63;

  float4 v = ((float4*)p)[tid];
  float s1 = v.x + v.y + v.z + v.w;
  float s2 = v.x * v.x + v.y * v.y + v.z * v.z + v.w * v.w;
  #pragma unroll
  for (int o = 32; o > 0; o >>= 1) {
    s1 += __shfl_down(s1, o);
    s2 += __shfl_down(s2, o);
  }
  __shared__ float red[8];
  if (lane == 0) { red[wave * 2] = s1; red[wave * 2 + 1] = s2; }
  __syncthreads();
  float t1 = red[0] + red[2] + red[4] + red[6];
  float t2 = red[1] + red[3] + red[5] + red[7];
  float mu = t1 * (1.0f / 1024.0f);
  float var = t2 * (1.0f / 1024.0f) - mu * mu;
  float rs = rsqrtf(var + 1e-5f);

  float4 g = ((const float4*)sg)[tid];
  float4 bb = ((const float4*)sb)[tid];
  v.x = fmaxf(0.0f, (v.x - mu) * rs * g.x + bb.x);
  v.y = fmaxf(0.0f, (v.y - mu) * rs * g.y + bb.y);
  v.z = fmaxf(0.0f, (v.z - mu) * rs * g.z + bb.z);
  v.w = fmaxf(0.0f, (v.w - mu) * rs * g.w + bb.w);
  ((float4*)p)[tid] = v;
}

extern "C" void kernel_launch(void* const* d_in, const int* in_sizes, int n_in,
                              void* d_out, int out_size, void* d_ws, size_t ws_size,
                              hipStream_t stream) {
  const float* x  = (const float*)d_in[0];
  const float* w  = (const float*)d_in[1];
  const float* cb = (const float*)d_in[2];
  const float* tg = (const float*)d_in[3];
  const float* tb = (const float*)d_in[4];
  const float* sg = (const float*)d_in[5];
  const float* sb = (const float*)d_in[6];
  float* out = (float*)d_out;
  unsigned short* ranks = (unsigned short*)d_ws;  // 64*1024*256*2 = 32 MB

  conv_rank_kernel<<<64 * 1024 / 4, 256, 0, stream>>>(x, w, cb, tg, tb, ranks);
  corr_kernel<<<64 * 36, 256, 0, stream>>>(ranks, out);
  ln_relu_kernel<<<64 * 1024, 256, 0, stream>>>(out, sg, sb);
}

// Round 4
// 680.953 us; speedup vs baseline: 1.0595x; 1.0595x over previous
//
#include <hip/hip_runtime.h>

// B=64, C=2, N=1024, T=13, D=256
// out: [B,N,N] fp32 = 268 MB; ws: centered ranks as bf16 bits [B,N,D] u16 = 32 MB

typedef __attribute__((ext_vector_type(4))) float f32x4;
typedef __attribute__((ext_vector_type(8))) short bf16x8;

__device__ __forceinline__ void load_lds16(const void* g, void* l) {
  __builtin_amdgcn_global_load_lds(
      (const __attribute__((address_space(1))) void*)g,
      (__attribute__((address_space(3))) void*)l, 16, 0, 0);
}

// ---------------------------------------------------------------------------
// K1: conv (bcnt,dct->bnd) + time-LayerNorm + Spearman rank -> (rank-128) bf16
// Block = 256 thr = 4 waves, 16 rows/block (4 rows/wave, 4 dims/lane).
// Grid = 65536 rows / 16 = 4096 blocks  (R3 bug: launched 1024 -> 3/4 of
// ranks stayed poison -> row-constant adj -> zero output for b>=16).
// w staged to LDS once per block (coalesced read, transposed padded layout).
// Rank counting: keys in LDS (reusing the w region), broadcast uint4 reads.
// ---------------------------------------------------------------------------
#define WT_STRIDE 260   // pad 256+4: scatter-write ~3-way max, b128-read aligned

__global__ __launch_bounds__(256) void conv_rank_kernel(
    const float* __restrict__ x, const float* __restrict__ w,
    const float* __restrict__ cb, const float* __restrict__ tg,
    const float* __restrict__ tb, unsigned short* __restrict__ ranks)
{
  __shared__ __align__(16) char smem[26 * WT_STRIDE * 4];  // 27040 B
  __shared__ float xs[16][26];
  float* wt = (float*)smem;              // wt[i*260 + d], i<26, d<256
  unsigned int* ksh = (unsigned int*)smem;  // reused after conv: ksh[r*256+d], 16 KB

  int tid = threadIdx.x;
  int wv = tid >> 6, lane = tid & 63;
  int row0 = blockIdx.x * 16;

  // stage w transposed: coalesced global read, LDS scatter (padded stride)
  #pragma unroll
  for (int it = 0; it < 26; ++it) {
    int idx = it * 256 + tid;            // 0..6655 == 256*26
    int d = idx / 26, i = idx - d * 26;
    wt[i * WT_STRIDE + d] = w[idx];
  }
  // stage x rows: xs[r][i], i = c*13+t
  for (int idx = tid; idx < 16 * 26; idx += 256) {
    int r = idx / 26, i = idx - r * 26;
    int rr = row0 + r;
    int b = rr >> 10, n = rr & 1023;
    int c = i / 13, t = i - c * 13;
    xs[r][i] = x[((size_t)(b * 2 + c) * 1024 + n) * 13 + t];
  }
  __syncthreads();

  int d0 = lane * 4;
  float4 cbv = ((const float4*)cb)[lane];
  float acc[4][4];
  #pragma unroll
  for (int r = 0; r < 4; ++r) {
    acc[r][0] = cbv.x; acc[r][1] = cbv.y; acc[r][2] = cbv.z; acc[r][3] = cbv.w;
  }

  // conv: one b128 w-fragment serves 4 rows x 4 dims (16 fma)
  #pragma unroll
  for (int i = 0; i < 26; ++i) {
    float4 w4 = *(const float4*)(wt + i * WT_STRIDE + d0);
    #pragma unroll
    for (int r = 0; r < 4; ++r) {
      float xr = xs[wv * 4 + r][i];      // wave-uniform -> LDS broadcast
      acc[r][0] = fmaf(w4.x, xr, acc[r][0]);
      acc[r][1] = fmaf(w4.y, xr, acc[r][1]);
      acc[r][2] = fmaf(w4.z, xr, acc[r][2]);
      acc[r][3] = fmaf(w4.w, xr, acc[r][3]);
    }
  }

  // per-row time-LN over D=256 (wave butterfly), then monotone u32 keys
  float4 tgv = ((const float4*)tg)[lane];
  float4 tbv = ((const float4*)tb)[lane];
  unsigned int key[4][4];
  #pragma unroll
  for (int r = 0; r < 4; ++r) {
    float s1 = acc[r][0] + acc[r][1] + acc[r][2] + acc[r][3];
    float s2 = acc[r][0]*acc[r][0] + acc[r][1]*acc[r][1]
             + acc[r][2]*acc[r][2] + acc[r][3]*acc[r][3];
    #pragma unroll
    for (int o = 32; o > 0; o >>= 1) {
      s1 += __shfl_xor(s1, o);
      s2 += __shfl_xor(s2, o);
    }
    float mu = s1 * (1.0f / 256.0f);
    float var = s2 * (1.0f / 256.0f) - mu * mu;
    float rs = rsqrtf(var + 1e-5f);
    #pragma unroll
    for (int s = 0; s < 4; ++s) {
      float val = (acc[r][s] - mu) * rs * (&tgv.x)[s] + (&tbv.x)[s];
      unsigned int u = __float_as_uint(val);
      key[r][s] = u ^ ((unsigned int)((int)u >> 31) | 0x80000000u);
    }
  }

  __syncthreads();   // all waves done reading wt/xs before key overwrite

  #pragma unroll
  for (int r = 0; r < 4; ++r) {
    uint4 kv = make_uint4(key[r][0], key[r][1], key[r][2], key[r][3]);
    *(uint4*)(ksh + (wv * 4 + r) * 256 + d0) = kv;
  }
  // wave-local consumption of wave-local writes: lockstep + lgkmcnt suffices

  int cnt[4][4] = {};
  #pragma unroll
  for (int r = 0; r < 4; ++r) {
    const uint4* kp = (const uint4*)(ksh + (wv * 4 + r) * 256);
    #pragma unroll 4
    for (int j = 0; j < 64; ++j) {
      uint4 q = kp[j];                   // broadcast ds_read_b128
      cnt[r][0] += (q.x < key[r][0]); cnt[r][0] += (q.y < key[r][0]);
      cnt[r][0] += (q.z < key[r][0]); cnt[r][0] += (q.w < key[r][0]);
      cnt[r][1] += (q.x < key[r][1]); cnt[r][1] += (q.y < key[r][1]);
      cnt[r][1] += (q.z < key[r][1]); cnt[r][1] += (q.w < key[r][1]);
      cnt[r][2] += (q.x < key[r][2]); cnt[r][2] += (q.y < key[r][2]);
      cnt[r][2] += (q.z < key[r][2]); cnt[r][2] += (q.w < key[r][2]);
      cnt[r][3] += (q.x < key[r][3]); cnt[r][3] += (q.y < key[r][3]);
      cnt[r][3] += (q.z < key[r][3]); cnt[r][3] += (q.w < key[r][3]);
    }
  }

  // r' = rank - 128 in [-128,127]: exact in bf16 (low 16 fp32 bits are 0)
  #pragma unroll
  for (int r = 0; r < 4; ++r) {
    int rowg = row0 + wv * 4 + r;
    ushort4 o;
    o.x = (unsigned short)(__float_as_uint((float)(cnt[r][0] - 128)) >> 16);
    o.y = (unsigned short)(__float_as_uint((float)(cnt[r][1] - 128)) >> 16);
    o.z = (unsigned short)(__float_as_uint((float)(cnt[r][2] - 128)) >> 16);
    o.w = (unsigned short)(__float_as_uint((float)(cnt[r][3] - 128)) >> 16);
    *(ushort4*)(ranks + (size_t)rowg * 256 + d0) = o;
  }
}

// ---------------------------------------------------------------------------
// K2: per batch S = R R^T (bf16 MFMA), adj = |S-64| / (norm^2+1e-8)
// SYMMETRIC: only upper-triangle tiles (ti<=tj); off-diag tiles write both
// directions (both store patterns are 16x64B segments -- equal efficiency).
// ---------------------------------------------------------------------------
__global__ __launch_bounds__(256) void corr_kernel(
    const unsigned short* __restrict__ ranks, float* __restrict__ out)
{
  int blk = blockIdx.x;
  int b = blk / 36;
  int t = blk - b * 36;
  int ti = 0, rem = t;
  while (rem >= 8 - ti) { rem -= 8 - ti; ++ti; }
  int tj = ti + rem;
  int trow = ti << 7;
  int tcol = tj << 7;
  const unsigned short* R = ranks + (size_t)b * 1024 * 256;
  float* O = out + (size_t)b * 1024 * 1024;

  __shared__ __align__(16) unsigned short As[128 * 64];
  __shared__ __align__(16) unsigned short Bs[128 * 64];

  int tid = threadIdx.x;
  int wave = tid >> 6, lane = tid & 63;
  int wrow = (wave >> 1) * 64, wcol = (wave & 1) * 64;

  f32x4 acc[4][4] = {};

  for (int kt = 0; kt < 4; ++kt) {
    int k0 = kt * 64;
    #pragma unroll
    for (int q = 0; q < 4; ++q) {
      int elem = q * 2048 + tid * 8;
      int r = elem >> 6;
      int c = elem & 63;
      load_lds16(R + (size_t)(trow + r) * 256 + k0 + c, As + elem);
      load_lds16(R + (size_t)(tcol + r) * 256 + k0 + c, Bs + elem);
    }
    __syncthreads();

    #pragma unroll
    for (int ks2 = 0; ks2 < 2; ++ks2) {
      int kk = ks2 * 32 + ((lane >> 4) << 3);
      bf16x8 af[4], bf[4];
      #pragma unroll
      for (int mi = 0; mi < 4; ++mi)
        af[mi] = *(const bf16x8*)(As + (wrow + mi * 16 + (lane & 15)) * 64 + kk);
      #pragma unroll
      for (int ni = 0; ni < 4; ++ni)
        bf[ni] = *(const bf16x8*)(Bs + (wcol + ni * 16 + (lane & 15)) * 64 + kk);
      #pragma unroll
      for (int mi = 0; mi < 4; ++mi) {
        #pragma unroll
        for (int ni = 0; ni < 4; ++ni)
          acc[mi][ni] = __builtin_amdgcn_mfma_f32_16x16x32_bf16(
              af[mi], bf[ni], acc[mi][ni], 0, 0, 0);
      }
    }
    __syncthreads();
  }

  float inv_den = 1.0f / (1398080.0f + 1e-8f);
  bool offdiag = (ti != tj);
  #pragma unroll
  for (int mi = 0; mi < 4; ++mi) {
    int r0 = trow + wrow + mi * 16 + ((lane >> 4) << 2);
    #pragma unroll
    for (int ni = 0; ni < 4; ++ni) {
      int c0 = tcol + wcol + ni * 16 + (lane & 15);
      float4 tv;
      #pragma unroll
      for (int v = 0; v < 4; ++v) {
        float adj = fabsf(acc[mi][ni][v] - 64.0f) * inv_den;
        O[(size_t)(r0 + v) * 1024 + c0] = adj;
        (&tv.x)[v] = adj;
      }
      if (offdiag)
        *(float4*)(O + (size_t)c0 * 1024 + r0) = tv;
    }
  }
}

// ---------------------------------------------------------------------------
// K3: in-place LayerNorm over last axis (N=1024) + static_g/static_b + ReLU
// ---------------------------------------------------------------------------
__global__ __launch_bounds__(256) void ln_relu_kernel(
    float* __restrict__ out, const float* __restrict__ sg,
    const float* __restrict__ sb)
{
  size_t row = blockIdx.x;
  float* p = out + row * 1024;
  int tid = threadIdx.x;
  int wave = tid >> 6, lane = tid & 63;

  float4 v = ((float4*)p)[tid];
  float s1 = v.x + v.y + v.z + v.w;
  float s2 = v.x * v.x + v.y * v.y + v.z * v.z + v.w * v.w;
  #pragma unroll
  for (int o = 32; o > 0; o >>= 1) {
    s1 += __shfl_down(s1, o);
    s2 += __shfl_down(s2, o);
  }
  __shared__ float red[8];
  if (lane == 0) { red[wave * 2] = s1; red[wave * 2 + 1] = s2; }
  __syncthreads();
  float t1 = red[0] + red[2] + red[4] + red[6];
  float t2 = red[1] + red[3] + red[5] + red[7];
  float mu = t1 * (1.0f / 1024.0f);
  float var = t2 * (1.0f / 1024.0f) - mu * mu;
  float rs = rsqrtf(var + 1e-5f);

  float4 g = ((const float4*)sg)[tid];
  float4 bb = ((const float4*)sb)[tid];
  v.x = fmaxf(0.0f, (v.x - mu) * rs * g.x + bb.x);
  v.y = fmaxf(0.0f, (v.y - mu) * rs * g.y + bb.y);
  v.z = fmaxf(0.0f, (v.z - mu) * rs * g.z + bb.z);
  v.w = fmaxf(0.0f, (v.w - mu) * rs * g.w + bb.w);
  ((float4*)p)[tid] = v;
}

extern "C" void kernel_launch(void* const* d_in, const int* in_sizes, int n_in,
                              void* d_out, int out_size, void* d_ws, size_t ws_size,
                              hipStream_t stream) {
  const float* x  = (const float*)d_in[0];
  const float* w  = (const float*)d_in[1];
  const float* cb = (const float*)d_in[2];
  const float* tg = (const float*)d_in[3];
  const float* tb = (const float*)d_in[4];
  const float* sg = (const float*)d_in[5];
  const float* sb = (const float*)d_in[6];
  float* out = (float*)d_out;
  unsigned short* ranks = (unsigned short*)d_ws;  // 64*1024*256*2 = 32 MB

  conv_rank_kernel<<<4096, 256, 0, stream>>>(x, w, cb, tg, tb, ranks);  // 65536 rows / 16
  corr_kernel<<<64 * 36, 256, 0, stream>>>(ranks, out);
  ln_relu_kernel<<<64 * 1024, 256, 0, stream>>>(out, sg, sb);
}